// Round 5
// baseline (368.728 us; speedup 1.0000x reference)
//
#include <hip/hip_runtime.h>

#define NB 2048
#define NM 128
#define ND 5
#define NFA 62
#define NFB 6
#define NFAN 68
#define NC 128
#define KP 96
#define ROWS (NB * NM)        // 262144
#define LDW 104               // ushort stride for W in LDS (2-way free banking)
#define LDC 132               // float stride for C transpose buffer
#define MAXLIST 16384

typedef __bf16 bf16x8 __attribute__((ext_vector_type(8)));
typedef float floatx4 __attribute__((ext_vector_type(4)));

__device__ __forceinline__ unsigned short f2bf(float x) {
    unsigned u = __builtin_bit_cast(unsigned, x);
    u += 0x7FFFu + ((u >> 16) & 1u);   // RNE
    return (unsigned short)(u >> 16);
}
__device__ __forceinline__ unsigned pack2(float a, float b) {
    return (unsigned)f2bf(a) | ((unsigned)f2bf(b) << 16);
}

// ---- prep: W_self (68x128 f32, k-major) -> wsb bf16 [c][96]; zero counter ----
__global__ __launch_bounds__(256) void prep_w(const float* __restrict__ W_self,
                                              unsigned short* __restrict__ wsb,
                                              int* __restrict__ counter) {
    const int i = blockIdx.x * 256 + threadIdx.x;
    if (i < NC * KP) {
        const int c = i / KP, f = i - c * KP;
        wsb[i] = (f < NFAN) ? f2bf(W_self[f * NC + c]) : (unsigned short)0;
    } else if (i == NC * KP) {
        *counter = 0;
    }
}

// ---- k1: build packed bf16 vxi rows into out[row][0..47] (dwords); sparse list ----
// one thread per output dword; everything coalesced.
__global__ __launch_bounds__(256) void k1_pack(
    const float* __restrict__ atoms,
    const float* __restrict__ bonds,
    const int*   __restrict__ edges,
    int* __restrict__ counter,
    int* __restrict__ list,
    unsigned* __restrict__ outu)
{
    const int g   = blockIdx.x * 256 + threadIdx.x;   // g < ROWS*48 exactly
    const int row = g / 48;
    const int h   = g - row * 48;

    unsigned val = 0;
    if (h < 31) {                       // atoms features 2h, 2h+1
        float2 v = *(const float2*)&atoms[(size_t)row * NFA + 2 * h];
        val = pack2(v.x, v.y);
    } else if (h < 34) {                // bond-sum features 62..67
        const int j0 = 2 * (h - 31);
        const float* bp = bonds + (size_t)row * (ND * NFB) + j0;
        float s0 = 0.f, s1 = 0.f;
        #pragma unroll
        for (int d = 0; d < ND; ++d) {
            float2 t = *(const float2*)&bp[d * NFB];
            s0 += t.x; s1 += t.y;
        }
        val = pack2(s0, s1);
    } else if (h == 47) {               // degree + sparse list (val stays 0 -> K pad)
        const int* e = edges + (size_t)row * ND;
        int deg = 0;
        #pragma unroll
        for (int j = 0; j < ND; ++j) deg += (e[j] >= 0);
        if (deg < ND) {
            int slot = atomicAdd(counter, 1);
            if (slot < MAXLIST) list[slot] = row | (deg << 24);
        }
    }
    outu[(size_t)row * NC + h] = val;   // zero pad for h=34..46
}

// ---- k2: out = relu(vxi @ W_self + b_self), vxi read from out rows (bf16 packed) ----
__global__ __launch_bounds__(256) void k2_gemm(
    const unsigned short* __restrict__ wsb,
    const float* __restrict__ b_self,
    float* out)
{
    __shared__ __align__(16) unsigned char smem[4 * 16 * LDC * 4];  // 33792 B, unioned
    unsigned short* s_w = (unsigned short*)smem;                    // 128*104 = 26624 B
    float (*s_c)[16][LDC] = (float (*)[16][LDC])smem;

    const int tid  = threadIdx.x;
    const int w    = tid >> 6, lane = tid & 63;
    const int col  = lane & 15, quad = lane >> 4;

    // stage W into LDS (padded stride), fully coalesced 16B chunks
    for (int i = tid; i < (NC * KP) / 8; i += 256) {
        const int c = i / (KP / 8);
        const int off = (i - c * (KP / 8)) * 8;
        *(bf16x8*)&s_w[c * LDW + off] = *(const bf16x8*)&wsb[c * KP + off];
    }
    __syncthreads();

    const int row0 = blockIdx.x * 64 + w * 16;
    const unsigned short* vx = (const unsigned short*)out;

    // A-fragments: 3 dwordx4 per lane, 16B aligned (row stride 512 B)
    const unsigned short* arow = vx + (size_t)(row0 + col) * (NC * 2) + quad * 8;
    bf16x8 a0 = *(const bf16x8*)(arow);
    bf16x8 a1 = *(const bf16x8*)(arow + 32);
    bf16x8 a2 = *(const bf16x8*)(arow + 64);

    floatx4 acc[8];
    #pragma unroll
    for (int t = 0; t < 8; ++t) { floatx4 z; z[0] = z[1] = z[2] = z[3] = 0.f; acc[t] = z; }

    const unsigned short* wb = s_w + col * LDW + quad * 8;
    #pragma unroll
    for (int ct = 0; ct < 8; ++ct) {
        bf16x8 w0 = *(const bf16x8*)(wb + ct * 16 * LDW);
        bf16x8 w1 = *(const bf16x8*)(wb + ct * 16 * LDW + 32);
        bf16x8 w2 = *(const bf16x8*)(wb + ct * 16 * LDW + 64);
        acc[ct] = __builtin_amdgcn_mfma_f32_16x16x32_bf16(a0, w0, acc[ct], 0, 0, 0);
        acc[ct] = __builtin_amdgcn_mfma_f32_16x16x32_bf16(a1, w1, acc[ct], 0, 0, 0);
        acc[ct] = __builtin_amdgcn_mfma_f32_16x16x32_bf16(a2, w2, acc[ct], 0, 0, 0);
    }
    __syncthreads();   // everyone done with s_w; smem becomes s_c

    // epilogue: bias+relu into LDS (C layout: col=lane&15, row=quad*4+r)
    #pragma unroll
    for (int ct = 0; ct < 8; ++ct) {
        const float bias = b_self[ct * 16 + col];
        #pragma unroll
        for (int r = 0; r < 4; ++r)
            s_c[w][quad * 4 + r][ct * 16 + col] = fmaxf(acc[ct][r] + bias, 0.f);
    }
    __builtin_amdgcn_wave_barrier();   // s_c slice is wave-private

    // full-line stores: 8 x dwordx4, 1 KB per instruction
    #pragma unroll
    for (int it = 0; it < 8; ++it) {
        const int gidx = it * 64 + lane;
        const int m = gidx >> 5, c4 = (gidx & 31) * 4;
        float4 v = *(const float4*)&s_c[w][m][c4];
        *(float4*)&out[(size_t)(row0 + m) * NC + c4] = v;
    }
}

// ---- k3: zni for rows with deg<5 (~10K entries), one wave per entry ----
__global__ __launch_bounds__(256) void k3_sparse(
    const float* __restrict__ atoms,
    const float* __restrict__ bonds,
    const int*   __restrict__ edges,
    const float* __restrict__ W_inner,
    const float* __restrict__ b_inner,
    const int* __restrict__ counter,
    const int* __restrict__ list,
    float* __restrict__ out)
{
    __shared__ float s_sf[4][NFAN];
    const int w = threadIdx.x >> 6, lane = threadIdx.x & 63;
    int n = *counter;
    if (n > MAXLIST) n = MAXLIST;

    for (int idx = blockIdx.x * 4 + w; idx < n; idx += gridDim.x * 4) {
        const int packed = list[idx];
        const int row = packed & 0xFFFFFF;
        const int d   = ((unsigned)packed) >> 24;
        const int* e = edges + (size_t)row * ND;
        const int e0 = e[0], e1 = e[1], e2 = e[2], e3 = e[3], e4 = e[4];
        const float* ab = atoms + (size_t)(row >> 7) * (NM * NFA);

        if (lane < NFA) {   // neighbor-atom sums, coalesced 248B gathers
            float sv = 0.f;
            if (e0 >= 0) sv += ab[e0 * NFA + lane];
            if (e1 >= 0) sv += ab[e1 * NFA + lane];
            if (e2 >= 0) sv += ab[e2 * NFA + lane];
            if (e3 >= 0) sv += ab[e3 * NFA + lane];
            if (e4 >= 0) sv += ab[e4 * NFA + lane];
            s_sf[w][lane] = sv;
        } else {            // lanes 62,63: bond sums, 3 features each
            const float* bp = bonds + (size_t)row * (ND * NFB);
            const int f0 = (lane - NFA) * 3;
            #pragma unroll
            for (int t = 0; t < 3; ++t) {
                const int j = f0 + t;
                float s = 0.f;
                #pragma unroll
                for (int dd = 0; dd < ND; ++dd) s += bp[dd * NFB + j];
                s_sf[w][NFA + j] = s;
            }
        }
        __builtin_amdgcn_wave_barrier();

        const int c0 = 2 * lane;
        float2 bi = *(const float2*)&b_inner[d * NC + c0];
        float acc0 = bi.x, acc1 = bi.y;
        const float* Wd = W_inner + (size_t)d * (NFAN * NC) + c0;
        #pragma unroll
        for (int f = 0; f < NFAN; ++f) {
            const float sv = s_sf[w][f];
            float2 wv = *(const float2*)&Wd[f * NC];
            acc0 += sv * wv.x; acc1 += sv * wv.y;
        }
        float2 cur = *(float2*)&out[(size_t)row * NC + c0];
        cur.x += fmaxf(acc0, 0.f);
        cur.y += fmaxf(acc1, 0.f);
        *(float2*)&out[(size_t)row * NC + c0] = cur;
        __builtin_amdgcn_wave_barrier();
    }
}

extern "C" void kernel_launch(void* const* d_in, const int* in_sizes, int n_in,
                              void* d_out, int out_size, void* d_ws, size_t ws_size,
                              hipStream_t stream) {
    const float* atoms   = (const float*)d_in[0];
    const float* bonds   = (const float*)d_in[1];
    const int*   edges   = (const int*)d_in[2];
    const float* W_inner = (const float*)d_in[3];
    const float* b_inner = (const float*)d_in[4];
    const float* W_self  = (const float*)d_in[5];
    const float* b_self  = (const float*)d_in[6];
    float* out = (float*)d_out;

    unsigned char* ws = (unsigned char*)d_ws;
    unsigned short* wsb = (unsigned short*)ws;          // 24576 B
    int* counter = (int*)(ws + 24576);
    int* list    = (int*)(ws + 24832);                  // MAXLIST ints (64 KB)

    prep_w<<<49, 256, 0, stream>>>(W_self, wsb, counter);
    k1_pack<<<ROWS * 48 / 256, 256, 0, stream>>>(atoms, bonds, edges, counter, list,
                                                 (unsigned*)out);
    k2_gemm<<<ROWS / 64, 256, 0, stream>>>(wsb, b_self, out);
    k3_sparse<<<512, 256, 0, stream>>>(atoms, bonds, edges, W_inner, b_inner,
                                       counter, list, out);
}